// Round 1
// baseline (316.690 us; speedup 1.0000x reference)
//
#include <hip/hip_runtime.h>
#include <math.h>

// ---------------------------------------------------------------------------
// Sizes: B=1024, x:(B,66,64) f32
// conv(32,1,5,5) VALID -> (B,32,62,60), +bias, relu, maxpool4 -> (B,32,62,15)
// flat view (B*62, 480) -> G1: xa = tanh(X@bn_w+bn_b) (.,64), z = X@g_w (.,32)
// graph: S = xa@xa^T, softmax rows, (topk mask is all-ones: TOPK==N==62),
//        diag<-1, deg_is = rsqrt(clip(rowsum,1)), adj = D S D, out = adj@z+gb
// stages 2/3: same on (62,32) inputs, fully fused per-batch in LDS
// maxpool3 (32->10) -> flatten 620 -> fc (620,3)
// ---------------------------------------------------------------------------

// ============================ conv + relu + pool4 ===========================
__global__ __launch_bounds__(256) void conv_pool_kernel(
    const float* __restrict__ x,      // (B,66,64)
    const float* __restrict__ cw,     // (32,1,5,5)
    const float* __restrict__ cb,     // (32,)
    float* __restrict__ hp)           // (B,29760) = (B,32,62,15) flat
{
    __shared__ float4 xs[66 * 17];    // 16 data float4 + 1 pad per row
    __shared__ float wls[800];
    __shared__ float bls[32];
    const int b = blockIdx.x;
    const int tid = threadIdx.x;

    const float4* xg = (const float4*)(x + (size_t)b * 4224);
    for (int idx = tid; idx < 1056; idx += 256)
        xs[(idx >> 4) * 17 + (idx & 15)] = xg[idx];
    for (int i = tid; i < 832; i += 256) {
        if (i < 800) wls[i] = cw[i];
        else         bls[i - 800] = cb[i - 800];
    }
    __syncthreads();

    // tasks: 16 channel-pairs x 62 rows
    for (int task = tid; task < 992; task += 256) {
        const int cg = task / 62;
        const int r  = task % 62;
        const int c0 = cg * 2;
        float w0[25], w1[25];
        #pragma unroll
        for (int i = 0; i < 25; ++i) { w0[i] = wls[c0*25 + i]; w1[i] = wls[c0*25 + 25 + i]; }
        const float b0 = bls[c0], b1 = bls[c0 + 1];

        float Af[5][4], Bf[5][4];
        #pragma unroll
        for (int di = 0; di < 5; ++di) {
            float4 t = xs[(r + di) * 17];
            Af[di][0] = t.x; Af[di][1] = t.y; Af[di][2] = t.z; Af[di][3] = t.w;
        }
        float* o0 = hp + (size_t)b * 29760 + c0 * 930 + r * 15;
        float* o1 = o0 + 930;

        #pragma unroll 3
        for (int jp = 0; jp < 15; ++jp) {
            #pragma unroll
            for (int di = 0; di < 5; ++di) {
                float4 t = xs[(r + di) * 17 + jp + 1];
                Bf[di][0] = t.x; Bf[di][1] = t.y; Bf[di][2] = t.z; Bf[di][3] = t.w;
            }
            float mm0 = -1e30f, mm1 = -1e30f;
            #pragma unroll
            for (int dj = 0; dj < 4; ++dj) {
                float s0 = b0, s1 = b1;
                #pragma unroll
                for (int di = 0; di < 5; ++di) {
                    #pragma unroll
                    for (int k = 0; k < 5; ++k) {
                        const int col = dj + k;
                        const float v = (col < 4) ? Af[di][col] : Bf[di][col - 4];
                        s0 = fmaf(v, w0[di * 5 + k], s0);
                        s1 = fmaf(v, w1[di * 5 + k], s1);
                    }
                }
                mm0 = fmaxf(mm0, s0); mm1 = fmaxf(mm1, s1);
            }
            o0[jp] = fmaxf(mm0, 0.f);   // pool(relu(v)) == relu(max v)
            o1[jp] = fmaxf(mm1, 0.f);
            #pragma unroll
            for (int di = 0; di < 5; ++di) {
                Af[di][0] = Bf[di][0]; Af[di][1] = Bf[di][1];
                Af[di][2] = Bf[di][2]; Af[di][3] = Bf[di][3];
            }
        }
    }
}

// =================== G1: (63488,480)@(480,96) + activations =================
__global__ __launch_bounds__(256) void g1_kernel(
    const float* __restrict__ X,    // (63488,480) == hp
    const float* __restrict__ bnw,  // (480,64)
    const float* __restrict__ bnb,  // (64,)
    const float* __restrict__ gw,   // (480,32)
    float* __restrict__ xa,         // (63488,64) tanh'ed
    float* __restrict__ z)          // (63488,32)
{
    __shared__ float4 Xs[128 * 9];  // 128 rows x (8 data f4 + 1 pad)
    __shared__ float4 Wt[96 * 9];   // transposed W tile: [col][8 k-f4 + pad]
    const int tid = threadIdx.x;
    const int m0 = blockIdx.x * 128;
    const int tx = tid & 15, ty = tid >> 4;

    float acc[8][6];
    #pragma unroll
    for (int i = 0; i < 8; ++i)
        #pragma unroll
        for (int j = 0; j < 6; ++j) acc[i][j] = 0.f;

    for (int kc = 0; kc < 15; ++kc) {
        #pragma unroll
        for (int i = 0; i < 4; ++i) {
            const int idx = tid + i * 256;          // 1024 = 128 rows x 8 f4
            const int row = idx >> 3, c4 = idx & 7;
            Xs[row * 9 + c4] = ((const float4*)X)[(size_t)(m0 + row) * 120 + kc * 8 + c4];
        }
        #pragma unroll
        for (int i = 0; i < 3; ++i) {
            const int idx = tid + i * 256;          // 768 = 96 cols x 8 f4
            const int j = idx >> 3, c4 = idx & 7;
            const int k0 = kc * 32 + c4 * 4;
            float4 v;
            if (j < 64) {
                v.x = bnw[(k0+0)*64 + j]; v.y = bnw[(k0+1)*64 + j];
                v.z = bnw[(k0+2)*64 + j]; v.w = bnw[(k0+3)*64 + j];
            } else {
                const int jj = j - 64;
                v.x = gw[(k0+0)*32 + jj]; v.y = gw[(k0+1)*32 + jj];
                v.z = gw[(k0+2)*32 + jj]; v.w = gw[(k0+3)*32 + jj];
            }
            Wt[j * 9 + c4] = v;
        }
        __syncthreads();
        #pragma unroll 4
        for (int c4 = 0; c4 < 8; ++c4) {
            float4 xv[8], wv[6];
            #pragma unroll
            for (int i = 0; i < 8; ++i) xv[i] = Xs[(ty + i * 16) * 9 + c4];
            #pragma unroll
            for (int j = 0; j < 6; ++j) wv[j] = Wt[(tx + j * 16) * 9 + c4];
            #pragma unroll
            for (int i = 0; i < 8; ++i)
                #pragma unroll
                for (int j = 0; j < 6; ++j) {
                    acc[i][j] = fmaf(xv[i].x, wv[j].x, acc[i][j]);
                    acc[i][j] = fmaf(xv[i].y, wv[j].y, acc[i][j]);
                    acc[i][j] = fmaf(xv[i].z, wv[j].z, acc[i][j]);
                    acc[i][j] = fmaf(xv[i].w, wv[j].w, acc[i][j]);
                }
        }
        __syncthreads();
    }
    #pragma unroll
    for (int i = 0; i < 8; ++i) {
        const size_t row = (size_t)m0 + ty + i * 16;
        #pragma unroll
        for (int j = 0; j < 6; ++j) {
            const int col = tx + j * 16;
            if (col < 64) xa[row * 64 + col] = tanhf(acc[i][j] + bnb[col]);
            else          z[row * 32 + (col - 64)] = acc[i][j];
        }
    }
}

// ============== shared tail: softmax/diag/deg-norm/adj@z + bias =============
// S: [64*68] floats, valid rows/cols 0..61 (stride 68). zf: stride 36.
__device__ __forceinline__ void graph_post(
    float* __restrict__ S, const float* __restrict__ zf,
    float* __restrict__ degis, const float* __restrict__ gb,
    float* __restrict__ outp, const int tid)
{
    if (tid < 248) {                       // 4 lanes per row
        const int n = tid >> 2, s = tid & 3;
        float* Sr = S + n * 68;
        float mx = -1e30f;
        for (int m = s; m < 62; m += 4) mx = fmaxf(mx, Sr[m]);
        mx = fmaxf(mx, __shfl_xor(mx, 1));
        mx = fmaxf(mx, __shfl_xor(mx, 2));
        float sum = 0.f;
        for (int m = s; m < 62; m += 4) { const float e = __expf(Sr[m] - mx); Sr[m] = e; sum += e; }
        sum += __shfl_xor(sum, 1);
        sum += __shfl_xor(sum, 2);
        const float inv = 1.f / sum;
        for (int m = s; m < 62; m += 4) Sr[m] *= inv;
    }
    __syncthreads();
    if (tid < 62) S[tid * 68 + tid] = 1.f;
    __syncthreads();
    if (tid < 248) {
        const int n = tid >> 2, s = tid & 3;
        const float* Sr = S + n * 68;
        float dg = 0.f;
        for (int m = s; m < 62; m += 4) dg += Sr[m];
        dg += __shfl_xor(dg, 1);
        dg += __shfl_xor(dg, 2);
        if (s == 0) degis[n] = rsqrtf(fmaxf(dg, 1.f));
    }
    __syncthreads();
    if (tid < 248) {
        const int n = tid >> 2, s = tid & 3;
        float* Sr = S + n * 68;
        for (int m = s; m < 62; m += 4) Sr[m] *= degis[m];
    }
    __syncthreads();
    {
        const int tx = tid & 15, ty = tid >> 4;
        const int n0 = ty * 4, o0 = tx * 2;
        float a[4][2] = {};
        for (int m = 0; m < 62; ++m) {
            const float z0 = zf[m * 36 + o0], z1 = zf[m * 36 + o0 + 1];
            #pragma unroll
            for (int i = 0; i < 4; ++i) {
                const float sv = S[(n0 + i) * 68 + m];
                a[i][0] = fmaf(sv, z0, a[i][0]);
                a[i][1] = fmaf(sv, z1, a[i][1]);
            }
        }
        const float gb0 = gb[o0], gb1 = gb[o0 + 1];
        #pragma unroll
        for (int i = 0; i < 4; ++i) {
            const int n = n0 + i;
            if (n < 62) {
                const float d = degis[n];
                outp[n * 32 + o0]     = fmaf(d, a[i][0], gb0);
                outp[n * 32 + o0 + 1] = fmaf(d, a[i][1], gb1);
            }
        }
    }
}

// ================= stage-1 graph block (xa, z from global) ==================
__global__ __launch_bounds__(256) void sogc_adj_kernel(
    const float* __restrict__ xa,   // (B,62,64)
    const float* __restrict__ z,    // (B,62,32)
    const float* __restrict__ gb,   // (32,)
    float* __restrict__ out)        // (B,62,32)
{
    __shared__ float4 xas[64 * 17];
    __shared__ float4 zs[62 * 9];
    __shared__ __align__(16) float S[64 * 68];
    __shared__ float degis[62];
    const int b = blockIdx.x;
    const int tid = threadIdx.x;

    const float4* xag = (const float4*)(xa + (size_t)b * 3968);
    for (int idx = tid; idx < 992; idx += 256)
        xas[(idx >> 4) * 17 + (idx & 15)] = xag[idx];
    const float4* zg = (const float4*)(z + (size_t)b * 1984);
    for (int idx = tid; idx < 496; idx += 256)
        zs[(idx >> 3) * 9 + (idx & 7)] = zg[idx];
    __syncthreads();

    {   // S = xa @ xa^T, 4x4 per thread
        const int tx = tid & 15, ty = tid >> 4;
        const int n0 = ty * 4, m0 = tx * 4;
        float acc[4][4] = {};
        #pragma unroll 4
        for (int c4 = 0; c4 < 16; ++c4) {
            float4 xv[4], wv[4];
            #pragma unroll
            for (int i = 0; i < 4; ++i) xv[i] = xas[(n0 + i) * 17 + c4];
            #pragma unroll
            for (int j = 0; j < 4; ++j) wv[j] = xas[(m0 + j) * 17 + c4];
            #pragma unroll
            for (int i = 0; i < 4; ++i)
                #pragma unroll
                for (int j = 0; j < 4; ++j) {
                    acc[i][j] = fmaf(xv[i].x, wv[j].x, acc[i][j]);
                    acc[i][j] = fmaf(xv[i].y, wv[j].y, acc[i][j]);
                    acc[i][j] = fmaf(xv[i].z, wv[j].z, acc[i][j]);
                    acc[i][j] = fmaf(xv[i].w, wv[j].w, acc[i][j]);
                }
        }
        #pragma unroll
        for (int i = 0; i < 4; ++i)
            #pragma unroll
            for (int j = 0; j < 4; ++j)
                if (n0 + i < 62 && m0 + j < 62) S[(n0 + i) * 68 + (m0 + j)] = acc[i][j];
    }
    __syncthreads();
    graph_post(S, (const float*)zs, degis, gb, out + (size_t)b * 1984, tid);
}

// ================ stages 2/3: fully fused per-batch SOGC ====================
__global__ __launch_bounds__(256) void sogc_stage_kernel(
    const float* __restrict__ xin,  // (B,62,32)
    const float* __restrict__ bnw,  // (32,64)
    const float* __restrict__ bnb,  // (64,)
    const float* __restrict__ gw,   // (32,32)
    const float* __restrict__ gb,   // (32,)
    float* __restrict__ out)        // (B,62,32)
{
    __shared__ float4 x4s[64 * 9];
    __shared__ __align__(16) float xas[64 * 68];
    __shared__ __align__(16) float S[64 * 68];
    __shared__ float4 zs[62 * 9];
    __shared__ __align__(16) float bnws[32 * 68];
    __shared__ __align__(16) float gws[32 * 36];
    __shared__ float degis[62];
    const int b = blockIdx.x;
    const int tid = threadIdx.x;
    const int tx = tid & 15, ty = tid >> 4;

    const float4* xg = (const float4*)(xin + (size_t)b * 1984);
    for (int idx = tid; idx < 496; idx += 256)
        x4s[(idx >> 3) * 9 + (idx & 7)] = xg[idx];
    for (int idx = tid; idx < 512; idx += 256) {       // bn_w: 512 f4
        const int k = idx >> 4, c4 = idx & 15;
        *(float4*)&bnws[k * 68 + c4 * 4] = ((const float4*)bnw)[idx];
    }
    {
        const int idx = tid;                            // g_w: 256 f4
        if (idx < 256) {
            const int k = idx >> 3, c4 = idx & 7;
            *(float4*)&gws[k * 36 + c4 * 4] = ((const float4*)gw)[idx];
        }
    }
    __syncthreads();

    {   // xa = tanh(x @ bnw + bnb), 4 rows x 4 cols per thread
        const int n0 = ty * 4, j0 = tx * 4;
        float acc[4][4] = {};
        const float* xf = (const float*)x4s;
        #pragma unroll 4
        for (int k = 0; k < 32; ++k) {
            const float4 wv = *(const float4*)&bnws[k * 68 + j0];
            #pragma unroll
            for (int i = 0; i < 4; ++i) {
                const float xv = xf[(n0 + i) * 36 + k];
                acc[i][0] = fmaf(xv, wv.x, acc[i][0]);
                acc[i][1] = fmaf(xv, wv.y, acc[i][1]);
                acc[i][2] = fmaf(xv, wv.z, acc[i][2]);
                acc[i][3] = fmaf(xv, wv.w, acc[i][3]);
            }
        }
        #pragma unroll
        for (int i = 0; i < 4; ++i)
            #pragma unroll
            for (int j = 0; j < 4; ++j)
                xas[(n0 + i) * 68 + j0 + j] = tanhf(acc[i][j] + bnb[j0 + j]);
    }
    {   // z = x @ gw, 4 rows x 2 cols per thread
        const int n0 = ty * 4, o0 = tx * 2;
        float acc[4][2] = {};
        const float* xf = (const float*)x4s;
        #pragma unroll 4
        for (int k = 0; k < 32; ++k) {
            const float w0 = gws[k * 36 + o0], w1 = gws[k * 36 + o0 + 1];
            #pragma unroll
            for (int i = 0; i < 4; ++i) {
                const float xv = xf[(n0 + i) * 36 + k];
                acc[i][0] = fmaf(xv, w0, acc[i][0]);
                acc[i][1] = fmaf(xv, w1, acc[i][1]);
            }
        }
        float* zf = (float*)zs;
        #pragma unroll
        for (int i = 0; i < 4; ++i)
            if (n0 + i < 62) {
                zf[(n0 + i) * 36 + o0]     = acc[i][0];
                zf[(n0 + i) * 36 + o0 + 1] = acc[i][1];
            }
    }
    __syncthreads();

    {   // S = xa @ xa^T
        const int n0 = ty * 4, m0 = tx * 4;
        float acc[4][4] = {};
        #pragma unroll 4
        for (int c4 = 0; c4 < 16; ++c4) {
            float4 xv[4], wv[4];
            #pragma unroll
            for (int i = 0; i < 4; ++i) xv[i] = *(const float4*)&xas[(n0 + i) * 68 + c4 * 4];
            #pragma unroll
            for (int j = 0; j < 4; ++j) wv[j] = *(const float4*)&xas[(m0 + j) * 68 + c4 * 4];
            #pragma unroll
            for (int i = 0; i < 4; ++i)
                #pragma unroll
                for (int j = 0; j < 4; ++j) {
                    acc[i][j] = fmaf(xv[i].x, wv[j].x, acc[i][j]);
                    acc[i][j] = fmaf(xv[i].y, wv[j].y, acc[i][j]);
                    acc[i][j] = fmaf(xv[i].z, wv[j].z, acc[i][j]);
                    acc[i][j] = fmaf(xv[i].w, wv[j].w, acc[i][j]);
                }
        }
        #pragma unroll
        for (int i = 0; i < 4; ++i)
            #pragma unroll
            for (int j = 0; j < 4; ++j)
                if (n0 + i < 62 && m0 + j < 62) S[(n0 + i) * 68 + (m0 + j)] = acc[i][j];
    }
    __syncthreads();
    graph_post(S, (const float*)zs, degis, gb, out + (size_t)b * 1984, tid);
}

// ======================= maxpool3 + flatten + FC ============================
__global__ __launch_bounds__(256) void pool_fc_kernel(
    const float* __restrict__ xin,  // (B,62,32)
    const float* __restrict__ fcw,  // (620,3)
    const float* __restrict__ fcb,  // (3,)
    float* __restrict__ outp)       // (B,3)
{
    const int b = blockIdx.x;
    const int tid = threadIdx.x;
    const float* xr = xin + (size_t)b * 1984;
    float a0 = 0.f, a1 = 0.f, a2 = 0.f;
    for (int t = tid; t < 620; t += 256) {
        const int n = t / 10, tt = t % 10;
        const float* p3 = xr + n * 32 + tt * 3;
        const float p = fmaxf(fmaxf(p3[0], p3[1]), p3[2]);
        a0 = fmaf(p, fcw[t * 3 + 0], a0);
        a1 = fmaf(p, fcw[t * 3 + 1], a1);
        a2 = fmaf(p, fcw[t * 3 + 2], a2);
    }
    #pragma unroll
    for (int off = 32; off; off >>= 1) {
        a0 += __shfl_down(a0, off);
        a1 += __shfl_down(a1, off);
        a2 += __shfl_down(a2, off);
    }
    __shared__ float red[4][3];
    const int wv = tid >> 6, ln = tid & 63;
    if (ln == 0) { red[wv][0] = a0; red[wv][1] = a1; red[wv][2] = a2; }
    __syncthreads();
    if (tid == 0) {
        outp[b * 3 + 0] = red[0][0] + red[1][0] + red[2][0] + red[3][0] + fcb[0];
        outp[b * 3 + 1] = red[0][1] + red[1][1] + red[2][1] + red[3][1] + fcb[1];
        outp[b * 3 + 2] = red[0][2] + red[1][2] + red[2][2] + red[3][2] + fcb[2];
    }
}

// ============================== launcher ====================================
extern "C" void kernel_launch(void* const* d_in, const int* in_sizes, int n_in,
                              void* d_out, int out_size, void* d_ws, size_t ws_size,
                              hipStream_t stream) {
    const float* x     = (const float*)d_in[0];
    const float* convw = (const float*)d_in[1];
    const float* convb = (const float*)d_in[2];
    const float* bnw1  = (const float*)d_in[3];
    const float* bnb1  = (const float*)d_in[4];
    const float* gw1   = (const float*)d_in[5];
    const float* gb1   = (const float*)d_in[6];
    const float* bnw2  = (const float*)d_in[7];
    const float* bnb2  = (const float*)d_in[8];
    const float* gw2   = (const float*)d_in[9];
    const float* gb2   = (const float*)d_in[10];
    const float* bnw3  = (const float*)d_in[11];
    const float* bnb3  = (const float*)d_in[12];
    const float* gw3   = (const float*)d_in[13];
    const float* gb3   = (const float*)d_in[14];
    const float* fcw   = (const float*)d_in[15];
    const float* fcb   = (const float*)d_in[16];

    char* ws = (char*)d_ws;
    // layout (bytes): hp[0 .. 121,927,680) ; xa[121,927,680 .. +16,252,928) ;
    // z[138,180,608 .. +8,126,464)  -> max 146,307,072 B
    float* hp   = (float*)(ws);
    float* xa   = (float*)(ws + 121927680);
    float* z    = (float*)(ws + 138180608);
    float* out1 = (float*)(ws);             // hp dead after g1
    float* out2 = (float*)(ws + 8126464);
    float* out3 = (float*)(ws);             // out1 dead after stage2

    conv_pool_kernel<<<1024, 256, 0, stream>>>(x, convw, convb, hp);
    g1_kernel<<<496, 256, 0, stream>>>(hp, bnw1, bnb1, gw1, xa, z);
    sogc_adj_kernel<<<1024, 256, 0, stream>>>(xa, z, gb1, out1);
    sogc_stage_kernel<<<1024, 256, 0, stream>>>(out1, bnw2, bnb2, gw2, gb2, out2);
    sogc_stage_kernel<<<1024, 256, 0, stream>>>(out2, bnw3, bnb3, gw3, gb3, out3);
    pool_fc_kernel<<<1024, 256, 0, stream>>>(out3, fcw, fcb, (float*)d_out);
}